// Round 8
// baseline (245.584 us; speedup 1.0000x reference)
//
#include <hip/hip_runtime.h>
#include <cstddef>

// B=16, h=8, Ch=32, H=W=56, N=3136
// out[b][n][hh*32+ch] = q[b][hh][n][ch] * dwconv(v)[b][hh][n][ch]
//
// R13: WRITE-GRANULE experiment. R5-R12 falsified occupancy, issue volume,
// redundancy, L2 co-residency, overlap, L2 working-set — all pinned at
// ~2.0 TB/s effective with compulsory bytes. The ONE never-varied axis:
// every prior block owned one head => out stores were 128-B chunks at 1-KB
// stride; 8 XCD L2s evict these lines interleaved => HBM sees ~random
// 128-B write granules (~20% page efficiency on HBM3E) => the 51-MB write
// stream alone costs ~60us and binds everything. This round: block = one
// output row x ALL 8 heads; conv*q parked in a 57-KB LDS row buffer, then
// stored as perfectly CONTIGUOUS 1-KB wave bursts (57 KB sequential/block).
// Reads use R5's proven rolling wave-private staging (2-deep pipeline),
// wave handles 2 heads (pairs (0,5)(1,6)(2,7)(3,4), tap-balanced 58/58/74/50).
// v re-reads across y-blocks are L2-absorbed (b-clustered per XCD).

#define BH 16
#define NH 8
#define CH 32
#define HW 56
#define NN (HW*HW)
#define ROWB (HW*CH*4)          // 7168 B per image row
#define WBF 2304                // wave-private buf: 72 px slots * 32 ch
#define OUTROWF 264             // out-LDS floats per px (256 + 8 pad)
// weight LDS layout [tap][ch]: w3 @0 (stride 64), w5 @576 (stride 96),
// w7 @2976 (stride 96); total 7680 floats.
#define W3O 0
#define W5O 576
#define W7O 2976
#define WTOT 7680

typedef float f32x4 __attribute__((ext_vector_type(4)));
typedef unsigned int u32x4 __attribute__((ext_vector_type(4)));

__device__ __forceinline__ f32x4 bload(__amdgpu_buffer_rsrc_t rs, int voff) {
    u32x4 u = __builtin_amdgcn_raw_buffer_load_b128(rs, voff, 0, 0);
    f32x4 f; __builtin_memcpy(&f, &u, 16); return f;
}

// One head, one output row y: R5 rolling conv (stage row dy -> window from
// LDS -> FMA), 2-deep global-load pipeline, q-mul, park into out-LDS row.
template<int K, int CT>
__device__ __forceinline__ void head_row(
    const float* __restrict__ q, const float* __restrict__ v,
    const float* __restrict__ whead,   // w_lds + tensor offset
    const float* __restrict__ bias_g,  // bias tensor + cbase
    float* __restrict__ outL, float* __restrict__ wb,
    int b, int hh, int cbase, int y, int lane)
{
    constexpr int P  = K / 2;
    constexpr int NR = 7 + K - 1;
    const int xseg = lane >> 3;         // 8 x-strips of 7 px
    const int chq  = lane & 7;          // 8 ch-quads
    const int x0   = xseg * 7;
    const int ch   = chq * 4;

    const size_t plane = ((size_t)b * NH + hh) * (size_t)NN * CH;
    const float* vb   = v + plane;
    const float* qrow = q + plane + (size_t)y * (HW * CH);
    const float* whc  = whead + cbase + ch;   // w4 = whc[tap*CT]

    // q prefetch (contiguous 1-KB bursts), consumed at park time.
    f32x4 qf[7];
#pragma unroll
    for (int i = 0; i < 7; ++i)
        qf[i] = *(const f32x4*)(qrow + (size_t)(x0 + i) * CH + ch);

    const f32x4 bias4 = *(const f32x4*)(bias_g + ch);
    f32x4 acc[7];
#pragma unroll
    for (int i = 0; i < 7; ++i) acc[i] = bias4;

    // 2-deep pipelined dy loop (fully unrolled -> ld indices constant).
    // OOB rows: num_records=0 -> loads return 0 = y zero-padding (R2-R4).
    f32x4 ld[2][7];
    {
        const int yy = y - P;
        const bool ok = (unsigned)yy < (unsigned)HW;
        __amdgpu_buffer_rsrc_t rs0 = __builtin_amdgcn_make_buffer_rsrc(
            (void*)(vb + (ptrdiff_t)yy * (HW * CH)), (short)0, ok ? ROWB : 0, 0x00020000);
#pragma unroll
        for (int k = 0; k < 7; ++k) ld[0][k] = bload(rs0, k * 1024 + lane * 16);
    }
#pragma unroll
    for (int dy = 0; dy < K; ++dy) {
        if (dy + 1 < K) {
            const int yy = y + dy + 1 - P;
            const bool ok = (unsigned)yy < (unsigned)HW;
            __amdgpu_buffer_rsrc_t rs = __builtin_amdgcn_make_buffer_rsrc(
                (void*)(vb + (ptrdiff_t)yy * (HW * CH)), (short)0, ok ? ROWB : 0, 0x00020000);
#pragma unroll
            for (int k = 0; k < 7; ++k) ld[(dy + 1) & 1][k] = bload(rs, k * 1024 + lane * 16);
        }
        // stage current row into wave-private buffer, slots 8..63
#pragma unroll
        for (int k = 0; k < 7; ++k)
            *(f32x4*)(wb + (k + 1) * 256 + lane * 4) = ld[dy & 1][k];

        // window from LDS (slots 0..7 / 64..71 are permanent zero x-pads)
        const float* rb = wb + (size_t)(x0 - P + 8) * CH + ch;
        f32x4 r[NR];
#pragma unroll
        for (int j = 0; j < NR; ++j)
            r[j] = *(const f32x4*)(rb + j * CH);

#pragma unroll
        for (int dx = 0; dx < K; ++dx) {
            const f32x4 w4 = *(const f32x4*)(whc + (dy * K + dx) * CT);
#pragma unroll
            for (int i = 0; i < 7; ++i)
                acc[i] += r[i + dx] * w4;
        }
    }

    // q-mul + park into out-LDS row [px][hh*32+ch] (2-way bank = free).
#pragma unroll
    for (int i = 0; i < 7; ++i)
        *(f32x4*)(outL + (size_t)(x0 + i) * OUTROWF + hh * CH + ch) = acc[i] * qf[i];
}

__device__ __forceinline__ void do_head(
    const float* q, const float* v,
    const float* w_lds,
    const float* b3, const float* b5, const float* b7,
    float* outL, float* wb, int b, int hh, int y, int lane)
{
    if (hh < 2)
        head_row<3, 64>(q, v, w_lds + W3O, b3 + hh * 32,        outL, wb, b, hh, hh * 32,       y, lane);
    else if (hh < 5)
        head_row<5, 96>(q, v, w_lds + W5O, b5 + hh * 32 - 64,   outL, wb, b, hh, hh * 32 - 64,  y, lane);
    else
        head_row<7, 96>(q, v, w_lds + W7O, b7 + hh * 32 - 160,  outL, wb, b, hh, hh * 32 - 160, y, lane);
}

__global__ __launch_bounds__(256, 1)   // 126.7 KB LDS -> 1 block/CU
void clusterformer_fused(const float* __restrict__ q, const float* __restrict__ v,
                         const float* __restrict__ w3, const float* __restrict__ b3,
                         const float* __restrict__ w5, const float* __restrict__ b5,
                         const float* __restrict__ w7, const float* __restrict__ b7,
                         float* __restrict__ out)
{
    __shared__ __align__(16) float w_lds[WTOT];          // 30720 B
    __shared__ __align__(16) float bufs[4 * WBF];        // 36864 B
    __shared__ __align__(16) float outL[HW * OUTROWF];   // 59136 B

    const int t    = threadIdx.x;
    const int wid  = t >> 6;
    const int lane = t & 63;

    // bid -> (b, y): b&7 = XCD (v/q planes XCD-local); same-b blocks are
    // consecutive slots -> neighbor y-blocks share halo rows in L2.
    const int bid  = blockIdx.x;       // 0..895
    const int xcd  = bid & 7;
    const int slot = bid >> 3;         // 0..111
    const int b_hi = (slot >= 56) ? 1 : 0;
    const int y    = slot - b_hi * 56;
    const int b    = (b_hi << 3) | xcd;

    // Stage all weights, layout [tap][ch] per tensor.
    for (int i = t; i < WTOT; i += 256) {
        float val;
        if (i < W5O) {                       // w3: 9 taps x 64 ch
            const int tap = i >> 6, c = i & 63;
            val = w3[c * 9 + tap];
        } else if (i < W7O) {                // w5: 25 taps x 96 ch
            const int j = i - W5O, tap = j / 96, c = j % 96;
            val = w5[c * 25 + tap];
        } else {                             // w7: 49 taps x 96 ch
            const int j = i - W7O, tap = j / 96, c = j % 96;
            val = w7[c * 49 + tap];
        }
        w_lds[i] = val;
    }

    // Permanent zero x-pads in the wave-private buffer: slots 0..7, 64..71.
    float* wb = bufs + wid * WBF;
    {
        f32x4 z = {0.f, 0.f, 0.f, 0.f};
        *(f32x4*)(wb + lane * 4) = z;             // slots 0..7
        *(f32x4*)(wb + 64 * CH + lane * 4) = z;   // slots 64..71
    }
    __syncthreads();                    // weights ready

    // Wave handles 2 heads, tap-balanced pairs (0,5)(1,6)(2,7)(3,4).
    const int h2tab[4] = {5, 6, 7, 4};
    do_head(q, v, w_lds, b3, b5, b7, outL, wb, b, wid,        y, lane);
    do_head(q, v, w_lds, b3, b5, b7, outL, wb, b, h2tab[wid], y, lane);

    __syncthreads();                    // all 8 head slices parked

    // Store the assembled row: 57,344 B fully CONTIGUOUS (the experiment).
    // iter m: wave wid stores px = m*4+wid as one 1-KB burst.
    float* orow = out + ((size_t)b * NN + (size_t)y * HW) * (NH * CH);
#pragma unroll
    for (int m = 0; m < 14; ++m) {
        const int px = m * 4 + wid;
        const f32x4 c4 = *(const f32x4*)(outL + (size_t)px * OUTROWF + lane * 4);
        *(f32x4*)(orow + (size_t)px * (NH * CH) + lane * 4) = c4;
    }
}

extern "C" void kernel_launch(void* const* d_in, const int* in_sizes, int n_in,
                              void* d_out, int out_size, void* d_ws, size_t ws_size,
                              hipStream_t stream) {
    const float* q  = (const float*)d_in[0];
    const float* v  = (const float*)d_in[1];
    const float* w3 = (const float*)d_in[2];
    const float* b3 = (const float*)d_in[3];
    const float* w5 = (const float*)d_in[4];
    const float* b5 = (const float*)d_in[5];
    const float* w7 = (const float*)d_in[6];
    const float* b7 = (const float*)d_in[7];
    float* out = (float*)d_out;

    const int grid = BH * HW;          // 896 blocks of 256 threads
    clusterformer_fused<<<grid, 256, 0, stream>>>(q, v, w3, b3, w5, b5, w7, b7, out);
}